// Round 9
// baseline (111.982 us; speedup 1.0000x reference)
//
#include <hip/hip_runtime.h>
#include <math.h>

#define B_ 32
#define C_ 64
#define L_ 16384
#define LT 64                           // l-columns per tile
#define NT 8                            // tiles per block (window = 512 l)
#define NBUF 3                          // staging buffers (depth-2)
#define NBLK (B_ * (L_ / (LT * NT)))    // 1024 blocks

typedef __attribute__((ext_vector_type(8))) short short8;
typedef __attribute__((ext_vector_type(4))) float f32x4;

__device__ __forceinline__ unsigned short f2bf(float x) {
  unsigned int u = __builtin_bit_cast(unsigned int, x);
  u += 0x7fffu + ((u >> 16) & 1u);   // RNE
  return (unsigned short)(u >> 16);
}

__device__ __forceinline__ float lrelu(float x) {
  return x >= 0.f ? x : 0.1f * x;
}

__device__ __forceinline__ void load_lds_16(const void* g, void* l) {
  __builtin_amdgcn_global_load_lds(
      (const __attribute__((address_space(1))) void*)g,
      (__attribute__((address_space(3))) void*)l, 16, 0, 0);
}

// ---------------------------------------------------------------------------
// Prep (tiny): kern4[b,c,4], att[b,c], wfrag = conv_w as bf16 A-frags in
// per-lane load order (unchanged from r4-r8).
// ---------------------------------------------------------------------------
__global__ void da_prep(const float* __restrict__ x1,
                        const float* __restrict__ W1,
                        const float* __restrict__ W2,
                        const float* __restrict__ ca_w1,
                        const float* __restrict__ ca_w2,
                        const float* __restrict__ conv_w,
                        float* __restrict__ kern4,
                        float* __restrict__ att,
                        unsigned short* __restrict__ wfrag) {
  int b = blockIdx.x;      // 32
  int t = threadIdx.x;     // 64
  __shared__ float x1s[64], h[64], a1[8];
  x1s[t] = x1[b * 64 + t];
  __syncthreads();
  {
    const float* w1r = W1 + t * 64;
    float s = 0.f;
    #pragma unroll
    for (int i = 0; i < 64; ++i) s = fmaf(x1s[i], w1r[i], s);
    h[t] = lrelu(s);
  }
  if (t < 8) {
    const float* cw = ca_w1 + t * 64;
    float a = 0.f;
    #pragma unroll
    for (int i = 0; i < 64; ++i) a = fmaf(x1s[i], cw[i], a);
    a1[t] = lrelu(a);
  }
  __syncthreads();
  #pragma unroll
  for (int kk = 0; kk < 3; ++kk) {
    const float* w2r = W2 + (t * 3 + kk) * 64;
    float s2 = 0.f;
    #pragma unroll
    for (int i = 0; i < 64; ++i) s2 = fmaf(h[i], w2r[i], s2);
    kern4[(b * 64 + t) * 4 + kk] = s2;
  }
  kern4[(b * 64 + t) * 4 + 3] = 0.f;
  {
    float a = 0.f;
    #pragma unroll
    for (int r = 0; r < 8; ++r) a = fmaf(a1[r], ca_w2[t * 8 + r], a);
    att[b * 64 + t] = 1.f / (1.f + expf(-a));
  }
  if (b == 0) {
    #pragma unroll
    for (int kt = 0; kt < 2; ++kt)
      #pragma unroll
      for (int mt = 0; mt < 4; ++mt)
        #pragma unroll
        for (int j = 0; j < 8; ++j) {
          float e = conv_w[(mt * 16 + (t & 15)) * 64 + kt * 32 + (t >> 4) * 8 + j];
          wfrag[(((kt * 4 + mt) * 64) + t) * 8 + j] = f2bf(e);
        }
  }
}

// ---------------------------------------------------------------------------
// Main: ONE barrier per iteration. LT=64, NBUF=3, depth-2, uniform vmcnt(16).
// Per iter: [vmcnt(16)] [step1: ALL reads of buf[cur] -> regs (q, xv, halos)]
// [lgkm0 + barrier] [step2: STAGE(t+2); wave3 right-halo from buf[nx1]]
// [step3: Phase A -> midT ALIASED into first 8KB of buf[cur]]
// [step4: Phase B MFMA (wave-private midT rows)] [step5: 16 stores].
//
// Why vmcnt(16) is exact & uniform: per wave per iter vmem = 4 glds (step2) +
// 16 stores (step5). Queue at iter-t top (old->new): stage(t+1)[4, issued
// t-1 step2], stores(t-1)[16]. vmcnt(16) retires stage(t+1), keeps stores.
// Cross-wave glds safety: issuer's own vmcnt(16) at iter t-1 retires its
// stage(t) ops BEFORE barrier(t-1); readers touch tile t after barrier(t-1).
// Right halo (tile t+1) retired at iter-t vmcnt, so its read sits AFTER
// barrier(t) (other waves' vmcnt also passed). Left halo via haloL strip
// (wave3 writes in step1 of t for t+1; barrier(t) orders vs wave0's read).
// midT aliasing safety: midT bytes [2048w,2048w+2048) = x0 rows [8w,8w+8);
// every wave's x0 reads happen in step1, all midT writes after the barrier.
// Buf recycle: stage(t+2)->buf[(t-1)%3]; its last readers (incl. Phase B on
// aliased midT(t-1)) finished before reaching barrier(t), stage is after.
// ---------------------------------------------------------------------------
__global__ __launch_bounds__(256, 3) void da_main(
    const float* __restrict__ x0,
    const float* __restrict__ conv_b,
    const float* __restrict__ kern4,
    const float* __restrict__ att,
    const unsigned short* __restrict__ wfrag,
    float* __restrict__ out) {
  __shared__ float x0s[NBUF][64 * LT];   // 3 x 16 KB (midT aliases cur's 8KB)
  __shared__ float haloL[2][64];

  int bid = blockIdx.x;            // 0..1023
  int b = bid >> 5;                // 32 windows per batch
  int base_l = (bid & 31) * (NT * LT);   // 512-l window
  int tid = threadIdx.x;
  int lane = tid & 63;
  int wave = tid >> 6;

  int m_lane = lane & 15;
  int qq = lane >> 4;
  int kbase = qq * 8;
  int wl = wave * 16 + m_lane;     // this thread's l (Phase B / epilogue)
  int cs = lane & 7;

  const float* xb = x0 + (size_t)(b * 64) * L_;

  // ---- async stage of tile t1 into buffer dd (4 glds/wave, 4 rows each)
  auto STAGE = [&](int t1, int dd) {
    #pragma unroll
    for (int i = 0; i < 4; ++i) {
      int rg = wave * 16 + i * 4;          // row-group of 4 rows (1 KB)
      int c = rg + (lane >> 4);
      int p = (lane & 15) ^ (c & 7);       // global chunk for LDS slot lane&15
      const float* gp = xb + (size_t)c * L_ + base_l + t1 * LT + (p << 2);
      load_lds_16(gp, &x0s[dd][rg * LT]);
    }
  };

  // ---- prologue staging first (deepest latency)
  STAGE(0, 0);
  STAGE(1, 1);

  // ---- pre-loop register loads
  short8 af[2][4];
  #pragma unroll
  for (int kt = 0; kt < 2; ++kt)
    #pragma unroll
    for (int mt = 0; mt < 4; ++mt)
      af[kt][mt] = *(const short8*)&wfrag[(((kt * 4 + mt) * 64) + lane) * 8];

  float4 kv = *(const float4*)&kern4[(b * 64 + lane) * 4];
  float k0 = kv.x, k1 = kv.y, k2 = kv.z;

  float cb_r[4][4], at_r[4][4];
  #pragma unroll
  for (int mt = 0; mt < 4; ++mt)
    #pragma unroll
    for (int r = 0; r < 4; ++r) {
      int o = mt * 16 + qq * 4 + r;
      cb_r[mt][r] = conv_b[o];
      at_r[mt][r] = att[b * 64 + o];
    }

  // window-edge halos (registers)
  float hl0 = 0.f, hnL = 0.f;
  if (wave == 0 && base_l > 0) hl0 = xb[(size_t)lane * L_ + base_l - 1];
  if (wave == 3 && base_l + NT * LT < L_)
    hnL = xb[(size_t)lane * L_ + base_l + NT * LT];
  if (wave == 0) haloL[0][lane] = hl0;

  __syncthreads();                 // drains vmcnt(0)+lgkmcnt(0) once, pre-loop

  int cur = 0, nx1 = 1, nx2 = 2;   // rotating buffer indices
  for (int t = 0; t < NT; ++t) {
    // uniform counted wait: retires stage(t+1); stores(t-1) stay in flight
    asm volatile("s_waitcnt vmcnt(16)" ::: "memory");

    // ---- step 1: ALL reads of buf[cur] into registers (pre-barrier)
    const float* row = &x0s[cur][lane * LT];
    float4 q[4];
    #pragma unroll
    for (int i = 0; i < 4; ++i)
      q[i] = *(const float4*)&row[((4 * wave + i) ^ cs) << 2];

    float prev;
    if (wave == 0) prev = haloL[t & 1][lane];
    else           prev = row[(((4 * wave - 1) ^ cs) << 2) + 3];
    float nxtv = 0.f;
    if (wave != 3) nxtv = row[((4 * wave + 4) ^ cs) << 2];
    if (wave == 3) haloL[(t + 1) & 1][lane] = q[3].w;   // left halo for t+1

    float xv[4][4];                 // residual x0 for epilogue
    #pragma unroll
    for (int mt = 0; mt < 4; ++mt)
      #pragma unroll
      for (int r = 0; r < 4; ++r) {
        int o = mt * 16 + qq * 4 + r;
        xv[mt][r] =
            x0s[cur][o * LT + (((wl >> 2) ^ (o & 7)) << 2) + (wl & 3)];
      }

    asm volatile("s_waitcnt lgkmcnt(0)" ::: "memory");
    __builtin_amdgcn_s_barrier();   // THE barrier: reads done, writes may begin
    asm volatile("" ::: "memory");  // fence: keep LDS ops below the barrier

    // ---- step 2: stage tile t+2 (buf nx2 free: all its readers passed bar)
    if (t + 2 < NT) STAGE(t + 2, nx2);

    // wave3 right halo from tile t+1 (post-barrier: all waves' stage retired)
    if (wave == 3)
      nxtv = (t == NT - 1) ? hnL : x0s[nx1][lane * LT + (cs << 2)];

    // ---- step 3: Phase A -> midT (aliased into first 8 KB of buf[cur])
    {
      unsigned short* mid = (unsigned short*)&x0s[cur][0];
      float xa[16] = {q[0].x, q[0].y, q[0].z, q[0].w, q[1].x, q[1].y,
                      q[1].z, q[1].w, q[2].x, q[2].y, q[2].z, q[2].w,
                      q[3].x, q[3].y, q[3].z, q[3].w};
      int lb = wave * 16;
      #pragma unroll
      for (int j = 0; j < 16; ++j) {
        float xm = (j == 0) ? prev : xa[j - 1];
        float xp = (j == 15) ? nxtv : xa[j + 1];
        float m = fmaf(k0, xm, fmaf(k1, xa[j], k2 * xp));
        mid[(lb + j) * 64 + (lane ^ ((j & 7) << 3))] = f2bf(lrelu(m));
      }
    }

    // ---- step 4: Phase B (wave-private midT rows; intra-wave lgkm only)
    f32x4 acc[4];
    #pragma unroll
    for (int mt = 0; mt < 4; ++mt) acc[mt] = (f32x4){0.f, 0.f, 0.f, 0.f};
    {
      const unsigned short* mid = (const unsigned short*)&x0s[cur][0];
      #pragma unroll
      for (int kt = 0; kt < 2; ++kt) {
        int cb = kt * 32 + kbase;
        const short8 bf =
            *(const short8*)&mid[wl * 64 + (cb ^ ((wl & 7) << 3))];
        #pragma unroll
        for (int mt = 0; mt < 4; ++mt)
          acc[mt] = __builtin_amdgcn_mfma_f32_16x16x32_bf16(af[kt][mt], bf,
                                                            acc[mt], 0, 0, 0);
      }
    }

    // ---- step 5: epilogue + 16 stores (never waited on mid-loop)
    {
      size_t obase = (size_t)(b * 64) * L_ + base_l + t * LT + wl;
      #pragma unroll
      for (int mt = 0; mt < 4; ++mt)
        #pragma unroll
        for (int r = 0; r < 4; ++r) {
          int o = mt * 16 + qq * 4 + r;
          out[obase + (size_t)o * L_] =
              acc[mt][r] + cb_r[mt][r] + xv[mt][r] * at_r[mt][r];
        }
    }

    int tmp = cur; cur = nx1; nx1 = nx2; nx2 = tmp;   // rotate buffers
  }
}

extern "C" void kernel_launch(void* const* d_in, const int* in_sizes, int n_in,
                              void* d_out, int out_size, void* d_ws, size_t ws_size,
                              hipStream_t stream) {
  const float* x0     = (const float*)d_in[0];
  const float* x1     = (const float*)d_in[1];
  const float* W1     = (const float*)d_in[2];
  const float* W2     = (const float*)d_in[3];
  const float* conv_w = (const float*)d_in[4];
  const float* conv_b = (const float*)d_in[5];
  const float* ca_w1  = (const float*)d_in[6];
  const float* ca_w2  = (const float*)d_in[7];
  float* out = (float*)d_out;

  float* kern4 = (float*)d_ws;                      // 32*64*4 = 8192 f
  float* att   = kern4 + B_ * C_ * 4;               // 2048 f
  unsigned short* wfrag = (unsigned short*)(att + B_ * C_);  // 4096 bf16

  da_prep<<<dim3(B_), dim3(64), 0, stream>>>(x1, W1, W2, ca_w1, ca_w2, conv_w,
                                             kern4, att, wfrag);
  da_main<<<dim3(NBLK), dim3(256), 0, stream>>>(x0, conv_b, kern4, att, wfrag,
                                                out);
}

// Round 10
// 67.949 us; speedup vs baseline: 1.6480x; 1.6480x over previous
//
#include <hip/hip_runtime.h>
#include <math.h>

#define B_ 32
#define C_ 64
#define L_ 16384
#define LT 32                           // l-columns per tile
#define NT 16                           // tiles per block (window = 512 l)
#define NBUF 4                          // staging buffers (depth-3 prefetch)
#define NBLK (B_ * (L_ / (LT * NT)))    // 1024 blocks -> exactly 4/CU resident

typedef __attribute__((ext_vector_type(8))) short short8;
typedef __attribute__((ext_vector_type(4))) float f32x4;

__device__ __forceinline__ unsigned short f2bf(float x) {
  unsigned int u = __builtin_bit_cast(unsigned int, x);
  u += 0x7fffu + ((u >> 16) & 1u);   // RNE
  return (unsigned short)(u >> 16);
}

__device__ __forceinline__ float lrelu(float x) {
  return x >= 0.f ? x : 0.1f * x;
}

__device__ __forceinline__ void load_lds_16(const void* g, void* l) {
  __builtin_amdgcn_global_load_lds(
      (const __attribute__((address_space(1))) void*)g,
      (__attribute__((address_space(3))) void*)l, 16, 0, 0);
}

// ---------------------------------------------------------------------------
// Prep (tiny): kern4[b,c,4], att[b,c], wfrag = conv_w as bf16 A-frags in
// per-lane load order (unchanged from r4-r8).
// ---------------------------------------------------------------------------
__global__ void da_prep(const float* __restrict__ x1,
                        const float* __restrict__ W1,
                        const float* __restrict__ W2,
                        const float* __restrict__ ca_w1,
                        const float* __restrict__ ca_w2,
                        const float* __restrict__ conv_w,
                        float* __restrict__ kern4,
                        float* __restrict__ att,
                        unsigned short* __restrict__ wfrag) {
  int b = blockIdx.x;      // 32
  int t = threadIdx.x;     // 64
  __shared__ float x1s[64], h[64], a1[8];
  x1s[t] = x1[b * 64 + t];
  __syncthreads();
  {
    const float* w1r = W1 + t * 64;
    float s = 0.f;
    #pragma unroll
    for (int i = 0; i < 64; ++i) s = fmaf(x1s[i], w1r[i], s);
    h[t] = lrelu(s);
  }
  if (t < 8) {
    const float* cw = ca_w1 + t * 64;
    float a = 0.f;
    #pragma unroll
    for (int i = 0; i < 64; ++i) a = fmaf(x1s[i], cw[i], a);
    a1[t] = lrelu(a);
  }
  __syncthreads();
  #pragma unroll
  for (int kk = 0; kk < 3; ++kk) {
    const float* w2r = W2 + (t * 3 + kk) * 64;
    float s2 = 0.f;
    #pragma unroll
    for (int i = 0; i < 64; ++i) s2 = fmaf(h[i], w2r[i], s2);
    kern4[(b * 64 + t) * 4 + kk] = s2;
  }
  kern4[(b * 64 + t) * 4 + 3] = 0.f;
  {
    float a = 0.f;
    #pragma unroll
    for (int r = 0; r < 8; ++r) a = fmaf(a1[r], ca_w2[t * 8 + r], a);
    att[b * 64 + t] = 1.f / (1.f + expf(-a));
  }
  if (b == 0) {
    #pragma unroll
    for (int kt = 0; kt < 2; ++kt)
      #pragma unroll
      for (int mt = 0; mt < 4; ++mt)
        #pragma unroll
        for (int j = 0; j < 8; ++j) {
          float e = conv_w[(mt * 16 + (t & 15)) * 64 + kt * 32 + (t >> 4) * 8 + j];
          wfrag[(((kt * 4 + mt) * 64) + t) * 8 + j] = f2bf(e);
        }
  }
}

// ---------------------------------------------------------------------------
// Main: r8 structure with DEPTH-3 prefetch (NBUF=4). LT=32, NT=16, 1024
// blocks, 36.75 KB LDS -> exactly 4 blocks/CU, ALL blocks resident.
// Per-wave in-loop vmem = 2 stage glds + 8 stores (uniform, no reg loads).
// Queue at iter-t wait (old->new): s(t+1)[2]@{t-2}, stores(t-2)[8],
// s(t+2)[2]@{t-1}, stores(t-1)[8], s(t+3)[2]@{t} = 22 ops.
// Steady vmcnt(20) retires s(t+1) -- issued TWO iterations ago (free wait)
// -- covering tile t (Phase A) and tile t+1 (right halo). Peeled waits:
// t=0: 4; t=1: 12; t=NT-3: 18; t=NT-2: 16; t=NT-1: none. Never 0 mid-loop.
// Buffer recycle: STAGE(t+3)->buf[(t-1)%4]; its last readers ran in Phase A
// of t-1, before bar_mid(t-1), and STAGE is issued after bar_mid(t-1). ✓
// All other structure (swizzles, halo strips, phase split) identical to r8.
// ---------------------------------------------------------------------------
__global__ __launch_bounds__(256, 4) void da_main(
    const float* __restrict__ x0,
    const float* __restrict__ conv_b,
    const float* __restrict__ kern4,
    const float* __restrict__ att,
    const unsigned short* __restrict__ wfrag,
    float* __restrict__ out) {
  __shared__ float x0s[NBUF][64 * LT];       // 4 x 8 KB
  __shared__ unsigned short midT[LT * 64];   // 4 KB
  __shared__ float haloL[2][64];

  int bid = blockIdx.x;            // 0..1023
  int b = bid >> 5;                // 32 windows per batch
  int base_l = (bid & 31) * (NT * LT);       // window = 512 l
  int tid = threadIdx.x;
  int lane = tid & 63;
  int wave = tid >> 6;

  int m_lane = lane & 15;
  int qq = lane >> 4;
  int kbase = qq * 8;
  int oh = wave >> 1;              // o-half for Phase B
  int lh = wave & 1;               // l-half for Phase B
  int wl = lh * 16 + m_lane;       // this thread's l (Phase B / epilogue)

  const float* xb = x0 + (size_t)(b * 64) * L_;

  // ---- async stage of tile t1 into buffer dd (2 glds/wave, 8 rows each)
  auto STAGE = [&](int t1, int dd) {
    #pragma unroll
    for (int i = 0; i < 2; ++i) {
      int rg = (wave * 2 + i) * 8;           // row-group base
      int c = rg + (lane >> 3);
      int g = (lane & 7) ^ (c & 7);          // global chunk for LDS slot lane&7
      const float* gp = xb + (size_t)c * L_ + base_l + t1 * LT + g * 4;
      load_lds_16(gp, &x0s[dd][rg * LT]);
    }
  };

  // ---- pre-loop register loads (drained before first glds)
  short8 af[2][2];                 // A-frags: this wave's o-half only
  #pragma unroll
  for (int kt = 0; kt < 2; ++kt)
    #pragma unroll
    for (int mt2 = 0; mt2 < 2; ++mt2)
      af[kt][mt2] =
          *(const short8*)&wfrag[(((kt * 4 + oh * 2 + mt2) * 64) + lane) * 8];

  float4 kv = *(const float4*)&kern4[(b * 64 + lane) * 4];
  float k0 = kv.x, k1 = kv.y, k2 = kv.z;

  float cb_r[2][4], at_r[2][4];
  #pragma unroll
  for (int mt2 = 0; mt2 < 2; ++mt2)
    #pragma unroll
    for (int r = 0; r < 4; ++r) {
      int o = oh * 32 + mt2 * 16 + qq * 4 + r;
      cb_r[mt2][r] = conv_b[o];
      at_r[mt2][r] = att[b * 64 + o];
    }

  // window-edge halos
  float hl0 = 0.f, hnL = 0.f;
  if (wave == 0 && base_l > 0) hl0 = xb[(size_t)lane * L_ + base_l - 1];
  if (wave == 3 && base_l + NT * LT < L_)
    hnL = xb[(size_t)lane * L_ + base_l + NT * LT];
  if (wave == 0) haloL[0][lane] = hl0;

  __syncthreads();                 // drains vmcnt(0)+lgkmcnt(0) of all above

  // ---- prologue: stage tiles 0, 1, 2
  STAGE(0, 0);
  STAGE(1, 1);
  STAGE(2, 2);

  int cur = 0, nx1 = 1, nx2 = 2, nx3 = 3;  // rotating buffer indices
  for (int t = 0; t < NT; ++t) {
    // issue tile t+3 (deepest overlap; buf nx3 free since bar_mid(t-1))
    if (t + 3 < NT) STAGE(t + 3, nx3);

    // counted wait: tiles t AND t+1 staged; stores + s(t+2..t+3) in flight
    if (t == 0)
      asm volatile("s_waitcnt vmcnt(4)" ::: "memory");
    else if (t == 1)
      asm volatile("s_waitcnt vmcnt(12)" ::: "memory");
    else if (t < NT - 3)
      asm volatile("s_waitcnt vmcnt(20)" ::: "memory");
    else if (t == NT - 3)
      asm volatile("s_waitcnt vmcnt(18)" ::: "memory");
    else if (t == NT - 2)
      asm volatile("s_waitcnt vmcnt(16)" ::: "memory");
    // t == NT-1: tile NT-1 already retired at t == NT-2; halo is hnL reg
    __builtin_amdgcn_s_barrier();            // bar1: tiles t, t+1 visible

    // ---- Phase A: depthwise 3-tap + lrelu -> midT rows [wave*8, wave*8+8)
    {
      int c = lane;
      int cs = c & 7;
      const float* row = &x0s[cur][c * LT];

      float4 q0 = *(const float4*)&row[((wave * 2 + 0) ^ cs) << 2];
      float4 q1 = *(const float4*)&row[((wave * 2 + 1) ^ cs) << 2];

      float prev, nxtv;
      if (wave == 0) {
        prev = (t == 0) ? hl0 : haloL[t & 1][c];
      } else {
        prev = row[(((wave * 2 - 1) ^ cs) << 2) + 3];   // word w0-1
      }
      if (wave == 3) {
        nxtv = (t == NT - 1) ? hnL : x0s[nx1][c * LT + (cs << 2)];
      } else {
        nxtv = row[((wave * 2 + 2) ^ cs) << 2];          // word w0+8
      }
      if (wave == 3 && t + 1 < NT) haloL[(t + 1) & 1][c] = q1.w;

      float m0 = fmaf(k0, prev, fmaf(k1, q0.x, k2 * q0.y));
      float m1 = fmaf(k0, q0.x, fmaf(k1, q0.y, k2 * q0.z));
      float m2 = fmaf(k0, q0.y, fmaf(k1, q0.z, k2 * q0.w));
      float m3 = fmaf(k0, q0.z, fmaf(k1, q0.w, k2 * q1.x));
      float m4 = fmaf(k0, q0.w, fmaf(k1, q1.x, k2 * q1.y));
      float m5 = fmaf(k0, q1.x, fmaf(k1, q1.y, k2 * q1.z));
      float m6 = fmaf(k0, q1.y, fmaf(k1, q1.z, k2 * q1.w));
      float m7 = fmaf(k0, q1.z, fmaf(k1, q1.w, k2 * nxtv));

      int lb = wave * 8;                      // lb ≡ 0 mod 8 -> swz = j<<3
      midT[(lb + 0) * 64 + (c ^ (0 << 3))] = f2bf(lrelu(m0));
      midT[(lb + 1) * 64 + (c ^ (1 << 3))] = f2bf(lrelu(m1));
      midT[(lb + 2) * 64 + (c ^ (2 << 3))] = f2bf(lrelu(m2));
      midT[(lb + 3) * 64 + (c ^ (3 << 3))] = f2bf(lrelu(m3));
      midT[(lb + 4) * 64 + (c ^ (4 << 3))] = f2bf(lrelu(m4));
      midT[(lb + 5) * 64 + (c ^ (5 << 3))] = f2bf(lrelu(m5));
      midT[(lb + 6) * 64 + (c ^ (6 << 3))] = f2bf(lrelu(m6));
      midT[(lb + 7) * 64 + (c ^ (7 << 3))] = f2bf(lrelu(m7));
    }

    // ---- xv pre-read (residual x0 from buf cur) so buf recycles at bar_mid
    float xv[2][4];
    #pragma unroll
    for (int mt2 = 0; mt2 < 2; ++mt2)
      #pragma unroll
      for (int r = 0; r < 4; ++r) {
        int o = oh * 32 + mt2 * 16 + qq * 4 + r;
        xv[mt2][r] =
            x0s[cur][o * LT + (((wl >> 2) ^ (o & 7)) << 2) + (wl & 3)];
      }

    asm volatile("s_waitcnt lgkmcnt(0)" ::: "memory");
    __builtin_amdgcn_s_barrier();            // bar_mid: midT ready, bufs free

    // ---- Phase B: 1x1 conv via 16x16x32 bf16 MFMA (o-half oh, l-half lh)
    f32x4 acc[2];
    acc[0] = (f32x4){0.f, 0.f, 0.f, 0.f};
    acc[1] = (f32x4){0.f, 0.f, 0.f, 0.f};
    #pragma unroll
    for (int kt = 0; kt < 2; ++kt) {
      int cb = kt * 32 + kbase;
      const short8 bf =
          *(const short8*)&midT[wl * 64 + (cb ^ ((wl & 7) << 3))];
      acc[0] = __builtin_amdgcn_mfma_f32_16x16x32_bf16(af[kt][0], bf, acc[0],
                                                       0, 0, 0);
      acc[1] = __builtin_amdgcn_mfma_f32_16x16x32_bf16(af[kt][1], bf, acc[1],
                                                       0, 0, 0);
    }

    // ---- Epilogue: + conv_b + x0*att, stores (never waited on mid-loop)
    {
      size_t obase = (size_t)(b * 64) * L_ + base_l + t * LT + wl;
      #pragma unroll
      for (int mt2 = 0; mt2 < 2; ++mt2)
        #pragma unroll
        for (int r = 0; r < 4; ++r) {
          int o = oh * 32 + mt2 * 16 + qq * 4 + r;
          out[obase + (size_t)o * L_] =
              acc[mt2][r] + cb_r[mt2][r] + xv[mt2][r] * at_r[mt2][r];
        }
    }

    int tmp = cur; cur = nx1; nx1 = nx2; nx2 = nx3; nx3 = tmp;  // rotate
  }
}

extern "C" void kernel_launch(void* const* d_in, const int* in_sizes, int n_in,
                              void* d_out, int out_size, void* d_ws, size_t ws_size,
                              hipStream_t stream) {
  const float* x0     = (const float*)d_in[0];
  const float* x1     = (const float*)d_in[1];
  const float* W1     = (const float*)d_in[2];
  const float* W2     = (const float*)d_in[3];
  const float* conv_w = (const float*)d_in[4];
  const float* conv_b = (const float*)d_in[5];
  const float* ca_w1  = (const float*)d_in[6];
  const float* ca_w2  = (const float*)d_in[7];
  float* out = (float*)d_out;

  float* kern4 = (float*)d_ws;                      // 32*64*4 = 8192 f
  float* att   = kern4 + B_ * C_ * 4;               // 2048 f
  unsigned short* wfrag = (unsigned short*)(att + B_ * C_);  // 4096 bf16

  da_prep<<<dim3(B_), dim3(64), 0, stream>>>(x1, W1, W2, ca_w1, ca_w2, conv_w,
                                             kern4, att, wfrag);
  da_main<<<dim3(NBLK), dim3(256), 0, stream>>>(x0, conv_b, kern4, att, wfrag,
                                                out);
}